// Round 2
// baseline (268.649 us; speedup 1.0000x reference)
//
#include <hip/hip_runtime.h>
#include <math.h>

// Problem constants (fixed by the reference problem instance).
#define SDIM 64          // spike waveform length S
#define KCL  32          // num_clusters K
#define FACTOR_D 3.0     // second_match_factor
#define MAXDIST_TH 1280.0f  // MAX_DIST * S = 20 * 64
#define MATCHED2_F 2.0f  // SPIKE_MATCHED_2

// ---------------------------------------------------------------------------
// P0: zero the f64 stats region (gsum[K*S] ++ gsq[K*S] ++ gcnt[K], contiguous)
// ---------------------------------------------------------------------------
__global__ void zero_ws_kernel(double* __restrict__ gstats) {
  const int total = KCL * SDIM * 2 + KCL;
  for (int i = threadIdx.x; i < total; i += blockDim.x) gstats[i] = 0.0;
}

// ---------------------------------------------------------------------------
// P1: per-cluster segment sums (f64). Wave = 4 rows x 16 lanes (float4 each).
// Rows with cluster 0 are skipped: their stats are never used (valid[0]=False).
// ---------------------------------------------------------------------------
__global__ __launch_bounds__(256) void stats_kernel(
    const float* __restrict__ spikes, const int* __restrict__ sortidx,
    double* __restrict__ gsum, double* __restrict__ gsq,
    double* __restrict__ gcnt, int n)
{
  __shared__ double s_sum[KCL][SDIM];
  __shared__ double s_sq[KCL][SDIM];
  __shared__ double s_cnt[KCL];
  for (int i = threadIdx.x; i < KCL * SDIM; i += blockDim.x) {
    (&s_sum[0][0])[i] = 0.0;
    (&s_sq[0][0])[i]  = 0.0;
  }
  if (threadIdx.x < KCL) s_cnt[threadIdx.x] = 0.0;
  __syncthreads();

  const int wave = threadIdx.x >> 6;   // 0..3
  const int lane = threadIdx.x & 63;
  const int lg   = lane >> 4;          // row subgroup 0..3
  const int sub  = lane & 15;          // 16 lanes x float4 = 64 floats
  const int s0   = sub * 4;

  for (long long base = (long long)blockIdx.x * 16; base < n;
       base += (long long)gridDim.x * 16) {
    const int row = (int)base + wave * 4 + lg;
    if (row < n) {
      const int c = sortidx[row];
      if (c > 0 && c < KCL) {
        const float4 v = *reinterpret_cast<const float4*>(
            spikes + (size_t)row * SDIM + s0);
        unsafeAtomicAdd(&s_sum[c][s0 + 0], (double)v.x);
        unsafeAtomicAdd(&s_sum[c][s0 + 1], (double)v.y);
        unsafeAtomicAdd(&s_sum[c][s0 + 2], (double)v.z);
        unsafeAtomicAdd(&s_sum[c][s0 + 3], (double)v.w);
        unsafeAtomicAdd(&s_sq[c][s0 + 0], (double)v.x * (double)v.x);
        unsafeAtomicAdd(&s_sq[c][s0 + 1], (double)v.y * (double)v.y);
        unsafeAtomicAdd(&s_sq[c][s0 + 2], (double)v.z * (double)v.z);
        unsafeAtomicAdd(&s_sq[c][s0 + 3], (double)v.w * (double)v.w);
        if (sub == 0) unsafeAtomicAdd(&s_cnt[c], 1.0);
      }
    }
  }
  __syncthreads();

  for (int i = threadIdx.x; i < KCL * SDIM; i += blockDim.x) {
    const double a = (&s_sum[0][0])[i];
    if (a != 0.0) unsafeAtomicAdd(&gsum[i], a);
    const double b = (&s_sq[0][0])[i];
    if (b != 0.0) unsafeAtomicAdd(&gsq[i], b);
  }
  if (threadIdx.x < KCL) {
    const double cc = s_cnt[threadIdx.x];
    if (cc != 0.0) unsafeAtomicAdd(&gcnt[threadIdx.x], cc);
  }
}

// ---------------------------------------------------------------------------
// P2: finalize means (transposed [S][K]), t2 = ||mean||^2, thr = 3*std, valid
// ---------------------------------------------------------------------------
__global__ void finalize_kernel(
    const double* __restrict__ gsum, const double* __restrict__ gsq,
    const double* __restrict__ gcnt, double* __restrict__ meansT,
    double* __restrict__ t2, double* __restrict__ thr, int* __restrict__ validk)
{
  __shared__ double s_var[KCL];
  __shared__ double s_t2[KCL];
  if (threadIdx.x < KCL) { s_var[threadIdx.x] = 0.0; s_t2[threadIdx.x] = 0.0; }
  __syncthreads();
  for (int i = threadIdx.x; i < KCL * SDIM; i += blockDim.x) {
    const int c = i / SDIM, s = i % SDIM;
    const double cnt  = gcnt[c];
    const double safe = fmax(cnt, 1.0);
    const double m    = gsum[i] / safe;
    const double var  = gsq[i] / safe - m * m;
    meansT[s * KCL + c] = m;
    unsafeAtomicAdd(&s_var[c], var);
    unsafeAtomicAdd(&s_t2[c], m * m);
  }
  __syncthreads();
  if (threadIdx.x < KCL) {
    const int c = threadIdx.x;
    thr[c]    = FACTOR_D * sqrt(fmax(s_var[c], 0.0));
    t2[c]     = s_t2[c];
    validk[c] = (c != 0 && gcnt[c] > 0.0) ? 1 : 0;
  }
}

// ---------------------------------------------------------------------------
// P3: pass-through outputs for every row (unmatched rows overwritten by P4).
// Outputs are fp32 (tuple concat promotes int32 ids to float32).
// ---------------------------------------------------------------------------
__global__ __launch_bounds__(256) void copy_kernel(
    const int* __restrict__ sortidx, const int* __restrict__ matchidx,
    const float* __restrict__ distance, float* __restrict__ out, int n)
{
  for (int r = blockIdx.x * blockDim.x + threadIdx.x; r < n;
       r += gridDim.x * blockDim.x) {
    out[r]         = (float)sortidx[r];
    out[n + r]     = (float)matchidx[r];
    out[2 * n + r] = distance[r];
  }
}

// ---------------------------------------------------------------------------
// P4: for each unmatched row (sort_idx==0): dist to each valid cluster,
// threshold mask, argmin with first-index tie-break, MAX_DIST override.
// One wave per row; lane = cluster (lanes 32..63 are inf duplicates).
// Rows found via chunked ballot scan (no workspace list needed).
// ---------------------------------------------------------------------------
__global__ __launch_bounds__(256) void assign_kernel(
    const float* __restrict__ spikes, const int* __restrict__ sortidx,
    const double* __restrict__ meansT, const double* __restrict__ t2g,
    const double* __restrict__ thrg, const int* __restrict__ validk,
    float* __restrict__ out, int n)
{
  __shared__ double s_mT[SDIM][KCL];   // transposed means: [s][c]
  __shared__ double s_t2[KCL];
  __shared__ double s_thr[KCL];
  __shared__ int    s_valid[KCL];
  for (int i = threadIdx.x; i < SDIM * KCL; i += blockDim.x)
    (&s_mT[0][0])[i] = meansT[i];
  if (threadIdx.x < KCL) {
    s_t2[threadIdx.x]    = t2g[threadIdx.x];
    s_thr[threadIdx.x]   = thrg[threadIdx.x];
    s_valid[threadIdx.x] = validk[threadIdx.x];
  }
  __syncthreads();

  const int wave = threadIdx.x >> 6;
  const int lane = threadIdx.x & 63;
  const int c    = lane & 31;
  const int gw   = blockIdx.x * (blockDim.x >> 6) + wave;
  const int nw   = gridDim.x * (blockDim.x >> 6);

  const bool active = (lane < KCL) && (s_valid[c] != 0);
  const double tc  = s_t2[c];
  const double thc = s_thr[c];

  // contiguous chunk per wave, 64-aligned for coalesced ballot loads
  long long chunk = ((long long)(n + nw - 1) / nw + 63) & ~63LL;
  const long long start = (long long)gw * chunk;
  long long end = start + chunk; if (end > n) end = n;

  for (long long rb = start; rb < end; rb += 64) {
    const long long rr = rb + lane;
    const int cv = (rr < end) ? sortidx[rr] : 1;
    unsigned long long mask = __ballot(cv == 0);
    while (mask) {
      const int b = __ffsll((unsigned long long)mask) - 1;
      mask &= (mask - 1);
      const long long r = rb + b;

      const float xv = spikes[(size_t)r * SDIM + lane];
      double x2 = 0.0, dot = 0.0;
#pragma unroll
      for (int s = 0; s < SDIM; ++s) {
        const double xs = (double)__shfl(xv, s, 64);
        x2  = fma(xs, xs, x2);
        dot = fma(xs, s_mT[s][c], dot);
      }

      double dist;
      int idx = c;
      if (active) {
        const double d2 = x2 - 2.0 * dot + tc;
        dist = sqrt(fmax(d2, 1e-12));
        if (dist > thc) dist = (double)INFINITY;  // threshold mask
      } else {
        dist = (double)INFINITY;                  // invalid cluster / dup lane
      }

      // min+argmin butterfly, first-index tie-break (matches jnp.argmin)
#pragma unroll
      for (int off = 32; off > 0; off >>= 1) {
        const double od = __shfl_xor(dist, off, 64);
        const int    oi = __shfl_xor(idx, off, 64);
        if (od < dist || (od == dist && oi < idx)) { dist = od; idx = oi; }
      }

      if (lane == 0) {
        const float minima = (float)dist;
        const int mz = (minima >= MAXDIST_TH) ? 0 : idx;
        out[r]         = (float)mz;
        out[n + r]     = MATCHED2_F;
        out[2 * n + r] = minima;
      }
    }
  }
}

// ---------------------------------------------------------------------------
extern "C" void kernel_launch(void* const* d_in, const int* in_sizes, int n_in,
                              void* d_out, int out_size, void* d_ws, size_t ws_size,
                              hipStream_t stream) {
  const float* spikes   = (const float*)d_in[0];
  const int*   sortidx  = (const int*)d_in[1];
  const int*   matchidx = (const int*)d_in[2];
  const float* distance = (const float*)d_in[3];
  const int n = in_sizes[1];
  if (n <= 0) return;

  // ws layout (all f64-aligned): gsum[K*S] gsq[K*S] gcnt[K] meansT[S*K] t2[K] thr[K] validk[K]
  double* gsum   = (double*)d_ws;
  double* gsq    = gsum + KCL * SDIM;
  double* gcnt   = gsq + KCL * SDIM;
  double* meansT = gcnt + KCL;
  double* t2     = meansT + KCL * SDIM;
  double* thr    = t2 + KCL;
  int*    validk = (int*)(thr + KCL);
  float*  out    = (float*)d_out;

  zero_ws_kernel<<<1, 256, 0, stream>>>(gsum);
  stats_kernel<<<1024, 256, 0, stream>>>(spikes, sortidx, gsum, gsq, gcnt, n);
  finalize_kernel<<<1, 256, 0, stream>>>(gsum, gsq, gcnt, meansT, t2, thr, validk);
  copy_kernel<<<2048, 256, 0, stream>>>(sortidx, matchidx, distance, out, n);
  assign_kernel<<<1024, 256, 0, stream>>>(spikes, sortidx, meansT, t2, thr, validk, out, n);
}